// Round 6
// baseline (383.284 us; speedup 1.0000x reference)
//
#include <hip/hip_runtime.h>

#define R_ 8
#define N_ 4096
#define D_ 128
#define BM 64                 // rows per tile
#define BKO 256               // outer K chunk -> 1 KB per adj row visit
#define NOUT (N_ / BKO)       // 16 outer steps
#define NKK (BKO / 32)        // 8 inner (MFMA) steps per outer

typedef __attribute__((ext_vector_type(8))) short bf16x8;
typedef __attribute__((ext_vector_type(4))) float f32x4;

__device__ __forceinline__ unsigned short f2bf(float f) {
  unsigned int u = __builtin_bit_cast(unsigned int, f);
  u += 0x7FFFu + ((u >> 16) & 1u);   // RNE
  return (unsigned short)(u >> 16);
}
__device__ __forceinline__ unsigned int pk2(float lo, float hi) {
  return (unsigned int)f2bf(lo) | ((unsigned int)f2bf(hi) << 16);
}

// async global->LDS, 16 B/lane; LDS dest = wave-uniform base + lane*16
__device__ __forceinline__ void gld16(const void* g, void* l) {
  using GP = const __attribute__((address_space(1))) unsigned int*;
  using LP = __attribute__((address_space(3))) unsigned int*;
  __builtin_amdgcn_global_load_lds((GP)g, (LP)l, 16, 0, 0);
}

// embT[d][n] = bf16(emb[n][d]) via LDS tile transpose (coalesced both sides)
__global__ __launch_bounds__(256) void k_init_embT(const float* __restrict__ emb,
                                                   unsigned short* __restrict__ embT) {
  __shared__ unsigned short t[D_][33];
  const int b = blockIdx.x;            // 128 blocks, 32 n-rows each
  const int tid = threadIdx.x;
#pragma unroll
  for (int j = 0; j < 16; ++j) {
    int flat = j * 256 + tid;
    int nl = flat >> 7, d = flat & 127;
    t[d][nl] = f2bf(emb[((size_t)(b * 32 + nl)) * D_ + d]);
  }
  __syncthreads();
#pragma unroll
  for (int j = 0; j < 16; ++j) {
    int flat = j * 256 + tid;
    int d = flat >> 5, nl = flat & 31;
    embT[(size_t)d * N_ + b * 32 + nl] = t[d][nl];
  }
}

__global__ void k_init_rel(const float* __restrict__ rel, unsigned short* __restrict__ relb) {
  int i = blockIdx.x * 256 + threadIdx.x;
  relb[i] = f2bf(rel[i]);
}

// ---------------- layer-1 GEMM: fp32 adj -> agg_p, also emits tiled bf16 adj copy ----
// adjb layout per (r,ntile): 512 chunks of 1 KB; chunk c = ((outer*NKK+kk)*2+wr)*2+mi,
// within chunk: 16B unit index == lane (= g*16+fr), i.e. exactly the A-fragment
// lane (fr,g) of the consuming wave needs. Writer and reader use the SAME keying.
__global__ __launch_bounds__(256, 2) void gcn_gemm1(
    const float* __restrict__ adj,            // [R][N][N] fp32
    const unsigned short* __restrict__ embT,  // [D][N] bf16 (L2-resident)
    unsigned short* __restrict__ adjb,        // [R*64 tiles][512 KB] bf16 tiled
    unsigned short* __restrict__ agg_p)       // [R][N][D] bf16
{
  __shared__ float As[BM * BKO];              // 64 KB, rows of 1 KB, slot-swizzled content

  const int tid  = threadIdx.x;
  const int lane = tid & 63;
  const int w    = tid >> 6;                  // 4 waves
  const int wr   = w >> 1, wc = w & 1;        // 2x2: 32 rows x 64 cols per wave
  const int fr   = lane & 15;
  const int g    = lane >> 4;                 // 0..3
  const int k8   = g * 8;
  const int cr4  = g * 4;

  const int ntile = blockIdx.x;               // 64
  const int r     = blockIdx.y;               // 8
  const int row0  = ntile * BM;

  const size_t tile16 = (size_t)(r * 64 + ntile) * 32768;  // 16B units per 512 KB tile

  f32x4 acc[2][4];
#pragma unroll
  for (int m = 0; m < 2; ++m)
#pragma unroll
    for (int n = 0; n < 4; ++n)
      acc[m][n] = (f32x4){0.f, 0.f, 0.f, 0.f};

  // B fragment base pointers (per lane), offset by k at use time
  const unsigned short* bptr[4];
#pragma unroll
  for (int n = 0; n < 4; ++n)
    bptr[n] = embT + (size_t)(wc * 64 + n * 16 + fr) * N_ + k8;

  bf16x8 bcur[4], bnxt[4];
#pragma unroll
  for (int n = 0; n < 4; ++n) bcur[n] = *(const bf16x8*)(bptr[n] + 0);

  for (int outer = 0; outer < NOUT; ++outer) {
    const int ko = outer * BKO;
    // ---- stage A: 16 gld16/thread, each instr = one 1 KB row chunk ----
#pragma unroll
    for (int i = 0; i < 16; ++i) {
      const int rw   = i * 4 + w;
      const int slot = lane ^ (rw & 7);       // source carries the swizzle
      gld16(adj + ((size_t)r * N_ + row0 + rw) * N_ + ko + slot * 4,
            As + rw * BKO);
    }
    __syncthreads();                          // DMA drained, tile resident

#pragma unroll
    for (int kk = 0; kk < NKK; ++kk) {
      // prefetch B for next kk (wrap harmless)
      int nko = ko + (kk + 1) * 32;
      if (kk == NKK - 1) nko = (outer + 1 < NOUT) ? (outer + 1) * BKO : 0;
#pragma unroll
      for (int n = 0; n < 4; ++n) bnxt[n] = *(const bf16x8*)(bptr[n] + nko);

      // A fragments: LDS read + convert; wc==0 waves also dump bf16 copy
      bf16x8 af[2];
#pragma unroll
      for (int mi = 0; mi < 2; ++mi) {
        const int row = wr * 32 + mi * 16 + fr;
        const int c0  = kk * 8 + g * 2;
        f32x4 a0 = *(const f32x4*)&As[row * BKO + ((c0     ) ^ (row & 7)) * 4];
        f32x4 a1 = *(const f32x4*)&As[row * BKO + ((c0 + 1) ^ (row & 7)) * 4];
        unsigned int* ap = (unsigned int*)&af[mi];
        ap[0] = pk2(a0.x, a0.y); ap[1] = pk2(a0.z, a0.w);
        ap[2] = pk2(a1.x, a1.y); ap[3] = pk2(a1.z, a1.w);
        if (wc == 0) {
          const size_t c = ((size_t)(outer * NKK + kk) * 2 + wr) * 2 + mi;
          *(bf16x8*)(adjb + (tile16 + c * 64 + lane) * 8) = af[mi];  // unit = lane (matches reader)
        }
      }
#pragma unroll
      for (int mi = 0; mi < 2; ++mi)
#pragma unroll
        for (int n = 0; n < 4; ++n)
          acc[mi][n] = __builtin_amdgcn_mfma_f32_16x16x32_bf16(af[mi], bcur[n], acc[mi][n], 0, 0, 0);
#pragma unroll
      for (int n = 0; n < 4; ++n) bcur[n] = bnxt[n];
    }
    __syncthreads();                          // protect LDS before next stage
  }

  unsigned short* gO = agg_p + ((size_t)r * N_ + row0) * D_;
#pragma unroll
  for (int mi = 0; mi < 2; ++mi)
#pragma unroll
    for (int n = 0; n < 4; ++n)
#pragma unroll
      for (int j = 0; j < 4; ++j) {
        int rl = wr * 32 + mi * 16 + cr4 + j;
        int cl = wc * 64 + n * 16 + fr;
        gO[(size_t)rl * D_ + cl] = f2bf(acc[mi][n][j]);
      }
}

// ---------------- layer-2 GEMM: dense bf16 tiled adj ----------------
__global__ __launch_bounds__(256, 4) void gcn_gemm2(
    const unsigned short* __restrict__ adjb,  // tiled bf16 (from gemm1)
    const unsigned short* __restrict__ embT,  // [D][N] bf16 (layer-2 emb)
    unsigned short* __restrict__ agg_p)       // [R][N][D] bf16
{
  __shared__ unsigned short Bt[BM * BKO];     // 32 KB: 32 chunks of 1 KB, linear

  const int tid  = threadIdx.x;
  const int lane = tid & 63;
  const int w    = tid >> 6;
  const int wr   = w >> 1, wc = w & 1;
  const int fr   = lane & 15;
  const int g    = lane >> 4;
  const int k8   = g * 8;
  const int cr4  = g * 4;

  const int ntile = blockIdx.x;
  const int r     = blockIdx.y;
  const int row0  = ntile * BM;
  const size_t tile16 = (size_t)(r * 64 + ntile) * 32768;

  f32x4 acc[2][4];
#pragma unroll
  for (int m = 0; m < 2; ++m)
#pragma unroll
    for (int n = 0; n < 4; ++n)
      acc[m][n] = (f32x4){0.f, 0.f, 0.f, 0.f};

  const unsigned short* bptr[4];
#pragma unroll
  for (int n = 0; n < 4; ++n)
    bptr[n] = embT + (size_t)(wc * 64 + n * 16 + fr) * N_ + k8;

  bf16x8 bcur[4], bnxt[4];
#pragma unroll
  for (int n = 0; n < 4; ++n) bcur[n] = *(const bf16x8*)(bptr[n] + 0);

  for (int outer = 0; outer < NOUT; ++outer) {
    // ---- stage 32 KB linearly: 8 gld16/thread, pure memcpy ----
#pragma unroll
    for (int i = 0; i < 8; ++i) {
      const int chunk = i * 4 + w;            // 0..31
      gld16(adjb + (tile16 + (size_t)outer * 2048 + chunk * 64) * 8 + lane * 8,
            Bt + chunk * 512);
    }
    __syncthreads();

#pragma unroll
    for (int kk = 0; kk < NKK; ++kk) {
      int nko = outer * BKO + (kk + 1) * 32;
      if (kk == NKK - 1) nko = (outer + 1 < NOUT) ? (outer + 1) * BKO : 0;
#pragma unroll
      for (int n = 0; n < 4; ++n) bnxt[n] = *(const bf16x8*)(bptr[n] + nko);

      bf16x8 af[2];
#pragma unroll
      for (int mi = 0; mi < 2; ++mi) {
        const int chunk = (kk * 2 + wr) * 2 + mi;
        af[mi] = *(const bf16x8*)&Bt[chunk * 512 + lane * 8];   // unit = lane (matches writer)
      }
#pragma unroll
      for (int mi = 0; mi < 2; ++mi)
#pragma unroll
        for (int n = 0; n < 4; ++n)
          acc[mi][n] = __builtin_amdgcn_mfma_f32_16x16x32_bf16(af[mi], bcur[n], acc[mi][n], 0, 0, 0);
#pragma unroll
      for (int n = 0; n < 4; ++n) bcur[n] = bnxt[n];
    }
    __syncthreads();
  }

  unsigned short* gO = agg_p + ((size_t)r * N_ + row0) * D_;
#pragma unroll
  for (int mi = 0; mi < 2; ++mi)
#pragma unroll
    for (int n = 0; n < 4; ++n)
#pragma unroll
      for (int j = 0; j < 4; ++j) {
        int rl = wr * 32 + mi * 16 + cr4 + j;
        int cl = wc * 64 + n * 16 + fr;
        gO[(size_t)rl * D_ + cl] = f2bf(acc[mi][n][j]);
      }
}

// Pass 2: tmp = agg_p @ rel^T summed over r; out = relu(mean_r); embT for next layer
__global__ __launch_bounds__(256) void gcn_pass2(
    const unsigned short* __restrict__ agg_p,  // [R][N][D] bf16
    const unsigned short* __restrict__ relb,   // [R][D][D] bf16
    float* __restrict__ out,                   // [N][D] f32
    unsigned short* __restrict__ embT,         // [D][N] bf16
    int write_out, int write_embT)
{
  const int tid  = threadIdx.x;
  const int lane = tid & 63;
  const int w    = tid >> 6;
  const int n0   = blockIdx.x * 16;
  const int col0 = w * 32;
  const int fr   = lane & 15;
  const int e8   = (lane >> 4) * 8;
  const int cr4  = (lane >> 4) * 4;

  f32x4 tacc[2];
  tacc[0] = (f32x4){0.f, 0.f, 0.f, 0.f};
  tacc[1] = (f32x4){0.f, 0.f, 0.f, 0.f};

  for (int r = 0; r < R_; ++r) {
    bf16x8 a[4], b[2][4];
#pragma unroll
    for (int kk = 0; kk < 4; ++kk)
      a[kk] = *(const bf16x8*)&agg_p[((size_t)r * N_ + n0 + fr) * D_ + kk * 32 + e8];
#pragma unroll
    for (int n = 0; n < 2; ++n)
#pragma unroll
      for (int kk = 0; kk < 4; ++kk)
        b[n][kk] = *(const bf16x8*)&relb[(size_t)r * D_ * D_ + (col0 + n * 16 + fr) * D_ + kk * 32 + e8];
#pragma unroll
    for (int n = 0; n < 2; ++n)
#pragma unroll
      for (int kk = 0; kk < 4; ++kk)
        tacc[n] = __builtin_amdgcn_mfma_f32_16x16x32_bf16(a[kk], b[n][kk], tacc[n], 0, 0, 0);
  }

#pragma unroll
  for (int n = 0; n < 2; ++n)
#pragma unroll
    for (int j = 0; j < 4; ++j) {
      int row = n0 + cr4 + j;
      int col = col0 + n * 16 + fr;
      float v = tacc[n][j] * 0.125f;
      v = v > 0.f ? v : 0.f;
      if (write_out)  out[(size_t)row * D_ + col] = v;
      if (write_embT) embT[(size_t)col * N_ + row] = f2bf(v);
    }
}

extern "C" void kernel_launch(void* const* d_in, const int* in_sizes, int n_in,
                              void* d_out, int out_size, void* d_ws, size_t ws_size,
                              hipStream_t stream) {
  const float* adj = (const float*)d_in[0];   // [R][N][N]
  const float* emb = (const float*)d_in[1];   // [N][D]
  const float* rel = (const float*)d_in[2];   // [R][D][D]
  float* out = (float*)d_out;                 // [N][D] f32

  unsigned short* embT  = (unsigned short*)d_ws;                 // 1 MB
  unsigned short* relb  = embT + (size_t)N_ * D_;                // 256 KB
  unsigned short* agg_p = relb + (size_t)R_ * D_ * D_;           // 8 MB
  unsigned short* adjb  = agg_p + (size_t)R_ * N_ * D_;          // 256 MB tiled bf16

  k_init_embT<<<N_ / 32, 256, 0, stream>>>(emb, embT);
  k_init_rel<<<(R_ * D_ * D_) / 256, 256, 0, stream>>>(rel, relb);

  dim3 grid(N_ / BM, R_);
  gcn_gemm1<<<grid, 256, 0, stream>>>(adj, embT, adjb, agg_p);
  gcn_pass2<<<N_ / 16, 256, 0, stream>>>(agg_p, relb, out, embT, 0, 1);
  gcn_gemm2<<<grid, 256, 0, stream>>>(adjb, embT, agg_p);
  gcn_pass2<<<N_ / 16, 256, 0, stream>>>(agg_p, relb, out, embT, 1, 0);
}